// Round 8
// baseline (220.280 us; speedup 1.0000x reference)
//
#include <hip/hip_runtime.h>
#include <math.h>

// VectorQuantizer, MFMA filter + exact-fp32 rescore.  N=32768 rows x K=8192
// codes, dim 64.
//   R4: 301us (1 blk/CU).  R5: 167us (4 blk/CU, LDS-bound).  R6: 223us (reg
//   residency drop).  R7: 170us (occupancy back to 42% but ~50us of barrier/
//   staging stall remains; bank conflicts 65K from 8-way-conflicted staging
//   writes; MFMA busy only 27.5us of 131us).
// R8 change: DROP LDS staging of B entirely.  The MFMA B-fragment for lane
// (s,q) is ebf[code=t*16+s][q*8..q*8+7] — one aligned 16B global dwordx4 from
// the L2-resident 1MB bf16 codebook.  Device L2 traffic for all B-frags =
// 1GB / 34.5TB/s ~= 29us, same order as the LDS reads it replaces, but this
// removes ALL staging writes, ALL bank conflicts, and ALL per-chunk barriers
// (3 __syncthreads left in the kernel).  Waves run independently.
//
// Exact numpy-fp32 semantics preserved (absmax 0 since R2 — DO NOT TOUCH):
//   S = sequential __fmaf_rn chain c=0..63; normx = numpy pairwise(n=64);
//   d = fl(normx - 2S) (2S exact); argmin = lowest index on ties.
// bf16 MFMA S~ error <= ~2e-5; exact-d quantization ~3.8e-6: codes within
// HALF_DELTA=4e-5 of per-row S~max (per k-slice) are a guaranteed superset of
// the exact argmin.  They are rescored bit-exactly; (d_bits<<13|k) u64
// atomicMin = value-then-lowest-index.  8 k-slices merge in vq_out.

#define DIM      64
#define NCODE    8192
#define NROWS    32768
#define RPB      256               // rows per block: 4 waves x 4 row-tiles x 16
#define KQ       1024              // codes per block (gridDim.y = 8)
#define NT       (KQ / 16)         // 64 t-groups of 16 codes
#define HALF_DELTA 4.0e-5f
#define CAND_CAP 2048

typedef __attribute__((ext_vector_type(8))) short frag8;   // 8 bf16
typedef __attribute__((ext_vector_type(4))) float f32x4;

__device__ __forceinline__ unsigned short f2bf_rne(float f) {
  unsigned u = __float_as_uint(f);
  return (unsigned short)((u + 0x7FFFu + ((u >> 16) & 1u)) >> 16);
}

// ---- kernel 0: codebook fp32 -> bf16 (RNE), 8192x64 = 1 MB in ws ----
__global__ __launch_bounds__(256) void cvt_emb(const float* __restrict__ emb,
                                               unsigned short* __restrict__ ebf) {
  const int i = (blockIdx.x * 256 + threadIdx.x) * 8;
  const float4 a = *(const float4*)(emb + i);
  const float4 c = *(const float4*)(emb + i + 4);
  union { unsigned short u[8]; uint4 v; } o;
  o.u[0] = f2bf_rne(a.x); o.u[1] = f2bf_rne(a.y);
  o.u[2] = f2bf_rne(a.z); o.u[3] = f2bf_rne(a.w);
  o.u[4] = f2bf_rne(c.x); o.u[5] = f2bf_rne(c.y);
  o.u[6] = f2bf_rne(c.z); o.u[7] = f2bf_rne(c.w);
  *(uint4*)(ebf + i) = o.v;
}

// ---- kernel 1: per (256-row group, 1024-code slice) ----
__global__ __launch_bounds__(256, 4) void vq_main(
    const float* __restrict__ x, const float* __restrict__ emb,
    const unsigned short* __restrict__ ebf,
    unsigned long long* __restrict__ wsbest)
{
  __shared__ float s_normx[RPB];
  __shared__ float s_mrow[RPB];
  __shared__ unsigned long long s_best[RPB];
  __shared__ unsigned s_cand[CAND_CAP];        // (row_l<<10 | k_local)
  __shared__ int s_cnt;

  const int tid  = threadIdx.x;
  const int lane = tid & 63;
  const int wave = tid >> 6;
  const int s    = lane & 15;                  // MFMA m / n index
  const int q    = lane >> 4;                  // MFMA quad
  const int rowbase = blockIdx.x * RPB;
  const int kbase   = blockIdx.y * KQ;
  const int b    = rowbase >> 10;
  const int hw0  = rowbase & 1023;             // multiple of 256; one image b
  const float* xb = x + (size_t)b * (DIM * 1024);

  if (tid == 0) s_cnt = 0;
  s_best[tid] = ~0ull;

  // normx — numpy pairwise_sum(n=64) bit-exact, streamed 8 loads at a time:
  // r8[j] = p[j] + p[8+j] + ... + p[56+j] (ascending m), then the fixed tree.
  {
    float r8[8];
#pragma unroll
    for (int m = 0; m < 8; ++m) {
#pragma unroll
      for (int j = 0; j < 8; ++j) {
        const float v = xb[(size_t)(m * 8 + j) * 1024 + hw0 + tid];
        const float pv = __fmul_rn(v, v);
        r8[j] = (m == 0) ? pv : __fadd_rn(r8[j], pv);
      }
    }
    const float t0 = __fadd_rn(r8[0], r8[1]), t1 = __fadd_rn(r8[2], r8[3]);
    const float t2 = __fadd_rn(r8[4], r8[5]), t3 = __fadd_rn(r8[6], r8[7]);
    s_normx[tid] = __fadd_rn(__fadd_rn(t0, t1), __fadd_rn(t2, t3));
  }

  // A-frags: wave owns 64 rows = 4 row-tiles of 16.  A[m=s][k=q*8+j].
  frag8 afr[4][2];
#pragma unroll
  for (int rt = 0; rt < 4; ++rt) {
    const float* xp = xb + hw0 + wave * 64 + rt * 16 + s;
#pragma unroll
    for (int h = 0; h < 2; ++h) {
      frag8 f;
#pragma unroll
      for (int j = 0; j < 8; ++j)
        f[j] = (short)f2bf_rne(xp[(size_t)(h * 32 + q * 8 + j) * 1024]);
      afr[rt][h] = f;
    }
  }

  // B-frags read straight from global (L2-resident 1MB bf16 codebook):
  // lane (s,q), t-group t: b0 = ebf[kbase + t*16 + s][q*8 .. q*8+7]   (16B)
  //                        b1 = ebf[kbase + t*16 + s][32+q*8 .. +7]   (16B)
  const frag8* gB = (const frag8*)ebf;         // 8 frag8 per code row
  const frag8* gp = gB + (size_t)(kbase + s) * 8 + q;   // + t*128, +4 for b1

  // ---- sweep A: per-row max of S~ ----
  f32x4 smax[4];
#pragma unroll
  for (int rt = 0; rt < 4; ++rt) smax[rt] = (f32x4){-1e30f, -1e30f, -1e30f, -1e30f};

#pragma unroll 4
  for (int t = 0; t < NT; ++t) {
    const frag8 b0 = gp[t * 128];
    const frag8 b1 = gp[t * 128 + 4];
#pragma unroll
    for (int rt = 0; rt < 4; ++rt) {
      f32x4 d = {0.f, 0.f, 0.f, 0.f};
      d = __builtin_amdgcn_mfma_f32_16x16x32_bf16(afr[rt][0], b0, d, 0, 0, 0);
      d = __builtin_amdgcn_mfma_f32_16x16x32_bf16(afr[rt][1], b1, d, 0, 0, 0);
      smax[rt][0] = fmaxf(smax[rt][0], d[0]);
      smax[rt][1] = fmaxf(smax[rt][1], d[1]);
      smax[rt][2] = fmaxf(smax[rt][2], d[2]);
      smax[rt][3] = fmaxf(smax[rt][3], d[3]);
    }
  }

  // reduce over the 16 code-columns (lane&15); D row = q*4+r
#pragma unroll
  for (int rt = 0; rt < 4; ++rt)
#pragma unroll
    for (int r = 0; r < 4; ++r) {
      float v = smax[rt][r];
      v = fmaxf(v, __shfl_xor(v, 1, 64));
      v = fmaxf(v, __shfl_xor(v, 2, 64));
      v = fmaxf(v, __shfl_xor(v, 4, 64));
      v = fmaxf(v, __shfl_xor(v, 8, 64));
      if (s == 0) s_mrow[wave * 64 + rt * 16 + q * 4 + r] = v;
    }
  __syncthreads();

  float thr[4][4];
#pragma unroll
  for (int rt = 0; rt < 4; ++rt)
#pragma unroll
    for (int r = 0; r < 4; ++r)
      thr[rt][r] = s_mrow[wave * 64 + rt * 16 + q * 4 + r] - HALF_DELTA;

  // ---- sweep B: recompute S~ (bit-identical), emit candidates ----
#pragma unroll 4
  for (int t = 0; t < NT; ++t) {
    const frag8 b0 = gp[t * 128];
    const frag8 b1 = gp[t * 128 + 4];
    const int kl = t * 16 + s;
#pragma unroll
    for (int rt = 0; rt < 4; ++rt) {
      f32x4 d = {0.f, 0.f, 0.f, 0.f};
      d = __builtin_amdgcn_mfma_f32_16x16x32_bf16(afr[rt][0], b0, d, 0, 0, 0);
      d = __builtin_amdgcn_mfma_f32_16x16x32_bf16(afr[rt][1], b1, d, 0, 0, 0);
#pragma unroll
      for (int r = 0; r < 4; ++r) {
        if (d[r] >= thr[rt][r]) {
          const int pos = atomicAdd(&s_cnt, 1);
          if (pos < CAND_CAP)
            s_cand[pos] = ((unsigned)(wave * 64 + rt * 16 + q * 4 + r) << 10) | (unsigned)kl;
        }
      }
    }
  }
  __syncthreads();

  // ---- exact rescore of candidates (bit-exact numpy fp32 pipeline) ----
  const int cnt = min(s_cnt, CAND_CAP);
  for (int i = tid; i < cnt; i += 256) {
    const unsigned e = s_cand[i];
    const int row_l = (int)(e >> 10);
    const int kg = kbase + (int)(e & 0x3FFu);
    const float* ep = emb + (size_t)kg * DIM;
    const float* xp = xb + hw0 + row_l;
    float S = 0.f;
#pragma unroll
    for (int c = 0; c < DIM; ++c) S = __fmaf_rn(xp[(size_t)c * 1024], ep[c], S);
    const float dd = __fsub_rn(s_normx[row_l], __fadd_rn(S, S));
    const unsigned long long pack =
        ((unsigned long long)__float_as_uint(dd) << 13) | (unsigned long long)kg;
    atomicMin(&s_best[row_l], pack);
  }
  __syncthreads();

  wsbest[(size_t)(rowbase + tid) * 8 + blockIdx.y] = s_best[tid];
}

// ---- kernel 2: merge slices, write indices + gather z_q ----
__global__ __launch_bounds__(256) void vq_out(
    const float* __restrict__ emb, const unsigned long long* __restrict__ wsbest,
    float* __restrict__ zq, float* __restrict__ idx_out)
{
  const int row = blockIdx.x * 256 + threadIdx.x;
  unsigned long long p = wsbest[(size_t)row * 8];
#pragma unroll
  for (int j = 1; j < 8; ++j) {
    const unsigned long long pj = wsbest[(size_t)row * 8 + j];
    if (pj < p) p = pj;                        // d-major, then lowest k
  }
  const int k = (int)(p & 0x1FFFull);
  idx_out[row] = (float)k;
  const int b = row >> 10, hw = row & 1023;
  const float* ep = emb + (size_t)k * DIM;
  float* zp = zq + (size_t)b * (DIM * 1024) + hw;
#pragma unroll
  for (int c = 0; c < DIM; ++c) zp[(size_t)c * 1024] = ep[c];
}

extern "C" void kernel_launch(void* const* d_in, const int* in_sizes, int n_in,
                              void* d_out, int out_size, void* d_ws, size_t ws_size,
                              hipStream_t stream) {
  const float* x   = (const float*)d_in[0];   // [32, 64, 32, 32] fp32
  const float* emb = (const float*)d_in[1];   // [8192, 64] fp32

  float* zq      = (float*)d_out;
  float* idx_out = zq + (size_t)NROWS * DIM;

  unsigned short*     ebf    = (unsigned short*)d_ws;                          // 1 MB
  unsigned long long* wsbest = (unsigned long long*)((char*)d_ws + (1 << 20)); // 2 MB

  cvt_emb<<<dim3(256), 256, 0, stream>>>(emb, ebf);
  vq_main<<<dim3(NROWS / RPB, NCODE / KQ), 256, 0, stream>>>(x, emb, ebf, wsbest);
  vq_out<<<dim3(NROWS / 256), 256, 0, stream>>>(emb, wsbest, zq, idx_out);
}

// Round 9
// 181.498 us; speedup vs baseline: 1.2137x; 1.2137x over previous
//
#include <hip/hip_runtime.h>
#include <math.h>

// VectorQuantizer, MFMA filter + exact-fp32 rescore.  N=32768 rows x K=8192
// codes, dim 64.
//   R5: 167us (LDS staging, 4 blk/CU).  R6: 223 (reg residency).  R7: 170.
//   R8: 220us REGRESSION — global B-frag loads were half-sparse: lane (s,q)
//   read code*128+q*16, so each wave load touched 64B of every 128B row
//   (16 scattered segments/inst, 2x transactions; busy pipes only 57/165us).
//   (Also learned: the 65K SQ_LDS_BANK_CONFLICT is constant w/ and w/o LDS
//   staging = ~255 cyc/CU = noise; R7's conflict theory was wrong.)
// R9 change: cvt_emb PERMUTES the bf16 codebook into MFMA fragment order:
//   16B chunk (g,h,s,q) = e[g*16+s][h*32+q*8 .. +8)  ->  index g*128+h*64+s*4+q.
//   A t-group's b0 wave-load union = 1KB dense (b1 = adjacent 1KB): perfectly
//   coalesced.  Same bf16 values, same fragments — only storage order changed.
//
// Exact numpy-fp32 semantics preserved (absmax 0 since R2 — DO NOT TOUCH):
//   S = sequential __fmaf_rn chain c=0..63; normx = numpy pairwise(n=64);
//   d = fl(normx - 2S) (2S exact); argmin = lowest index on ties.
// bf16 MFMA S~ error <= ~2e-5; exact-d quantization ~3.8e-6: codes within
// HALF_DELTA=4e-5 of per-row S~max (per k-slice) are a guaranteed superset of
// the exact argmin.  They are rescored bit-exactly; (d_bits<<13|k) u64
// atomicMin = value-then-lowest-index.  8 k-slices merge in vq_out.

#define DIM      64
#define NCODE    8192
#define NROWS    32768
#define RPB      256               // rows per block: 4 waves x 4 row-tiles x 16
#define KQ       1024              // codes per block (gridDim.y = 8)
#define NT       (KQ / 16)         // 64 t-groups of 16 codes
#define HALF_DELTA 4.0e-5f
#define CAND_CAP 2048

typedef __attribute__((ext_vector_type(8))) short frag8;   // 8 bf16
typedef __attribute__((ext_vector_type(4))) float f32x4;

__device__ __forceinline__ unsigned short f2bf_rne(float f) {
  unsigned u = __float_as_uint(f);
  return (unsigned short)((u + 0x7FFFu + ((u >> 16) & 1u)) >> 16);
}

// ---- kernel 0: codebook fp32 -> bf16 (RNE), PERMUTED to fragment order ----
// chunk index (16B units): g*128 + h*64 + s*4 + q  for code k=g*16+s,
// channels c = h*32 + q*8 .. +8.
__global__ __launch_bounds__(256) void cvt_emb(const float* __restrict__ emb,
                                               unsigned short* __restrict__ ebp) {
  const int chunk = blockIdx.x * 256 + threadIdx.x;   // 0..65535
  const int i = chunk * 8;                            // source float index
  const int k = i >> 6, c = i & 63;
  const int h = c >> 5, q = (c >> 3) & 3;
  const int g = k >> 4, s = k & 15;
  const float4 a = *(const float4*)(emb + i);
  const float4 b2 = *(const float4*)(emb + i + 4);
  union { unsigned short u[8]; uint4 v; } o;
  o.u[0] = f2bf_rne(a.x);  o.u[1] = f2bf_rne(a.y);
  o.u[2] = f2bf_rne(a.z);  o.u[3] = f2bf_rne(a.w);
  o.u[4] = f2bf_rne(b2.x); o.u[5] = f2bf_rne(b2.y);
  o.u[6] = f2bf_rne(b2.z); o.u[7] = f2bf_rne(b2.w);
  const int dst = g * 128 + h * 64 + s * 4 + q;
  *(uint4*)(ebp + (size_t)dst * 8) = o.v;
}

// ---- kernel 1: per (256-row group, 1024-code slice) ----
__global__ __launch_bounds__(256, 4) void vq_main(
    const float* __restrict__ x, const float* __restrict__ emb,
    const unsigned short* __restrict__ ebp,
    unsigned long long* __restrict__ wsbest)
{
  __shared__ float s_normx[RPB];
  __shared__ float s_mrow[RPB];
  __shared__ unsigned long long s_best[RPB];
  __shared__ unsigned s_cand[CAND_CAP];        // (row_l<<10 | k_local)
  __shared__ int s_cnt;

  const int tid  = threadIdx.x;
  const int lane = tid & 63;
  const int wave = tid >> 6;
  const int s    = lane & 15;                  // MFMA m / n index
  const int q    = lane >> 4;                  // MFMA quad
  const int rowbase = blockIdx.x * RPB;
  const int kbase   = blockIdx.y * KQ;
  const int b    = rowbase >> 10;
  const int hw0  = rowbase & 1023;             // multiple of 256; one image b
  const float* xb = x + (size_t)b * (DIM * 1024);

  if (tid == 0) s_cnt = 0;
  s_best[tid] = ~0ull;

  // normx — numpy pairwise_sum(n=64) bit-exact, streamed 8 loads at a time:
  // r8[j] = p[j] + p[8+j] + ... + p[56+j] (ascending m), then the fixed tree.
  {
    float r8[8];
#pragma unroll
    for (int m = 0; m < 8; ++m) {
#pragma unroll
      for (int j = 0; j < 8; ++j) {
        const float v = xb[(size_t)(m * 8 + j) * 1024 + hw0 + tid];
        const float pv = __fmul_rn(v, v);
        r8[j] = (m == 0) ? pv : __fadd_rn(r8[j], pv);
      }
    }
    const float t0 = __fadd_rn(r8[0], r8[1]), t1 = __fadd_rn(r8[2], r8[3]);
    const float t2 = __fadd_rn(r8[4], r8[5]), t3 = __fadd_rn(r8[6], r8[7]);
    s_normx[tid] = __fadd_rn(__fadd_rn(t0, t1), __fadd_rn(t2, t3));
  }

  // A-frags: wave owns 64 rows = 4 row-tiles of 16.  A[m=s][k=q*8+j].
  frag8 afr[4][2];
#pragma unroll
  for (int rt = 0; rt < 4; ++rt) {
    const float* xp = xb + hw0 + wave * 64 + rt * 16 + s;
#pragma unroll
    for (int h = 0; h < 2; ++h) {
      frag8 f;
#pragma unroll
      for (int j = 0; j < 8; ++j)
        f[j] = (short)f2bf_rne(xp[(size_t)(h * 32 + q * 8 + j) * 1024]);
      afr[rt][h] = f;
    }
  }

  // B-frags from permuted codebook: for t-group t (global g = kbase/16 + t),
  // lane (s,q):  b0 = P16[g*128 + s*4 + q],  b1 = P16[g*128 + 64 + s*4 + q].
  // Wave union per load = 1KB dense contiguous.
  const frag8* pp = (const frag8*)ebp + (size_t)(kbase >> 4) * 128 + s * 4 + q;

  // ---- sweep A: per-row max of S~ ----
  f32x4 smax[4];
#pragma unroll
  for (int rt = 0; rt < 4; ++rt) smax[rt] = (f32x4){-1e30f, -1e30f, -1e30f, -1e30f};

#pragma unroll 4
  for (int t = 0; t < NT; ++t) {
    const frag8 b0 = pp[t * 128];
    const frag8 b1 = pp[t * 128 + 64];
#pragma unroll
    for (int rt = 0; rt < 4; ++rt) {
      f32x4 d = {0.f, 0.f, 0.f, 0.f};
      d = __builtin_amdgcn_mfma_f32_16x16x32_bf16(afr[rt][0], b0, d, 0, 0, 0);
      d = __builtin_amdgcn_mfma_f32_16x16x32_bf16(afr[rt][1], b1, d, 0, 0, 0);
      smax[rt][0] = fmaxf(smax[rt][0], d[0]);
      smax[rt][1] = fmaxf(smax[rt][1], d[1]);
      smax[rt][2] = fmaxf(smax[rt][2], d[2]);
      smax[rt][3] = fmaxf(smax[rt][3], d[3]);
    }
  }

  // reduce over the 16 code-columns (lane&15); D row = q*4+r
#pragma unroll
  for (int rt = 0; rt < 4; ++rt)
#pragma unroll
    for (int r = 0; r < 4; ++r) {
      float v = smax[rt][r];
      v = fmaxf(v, __shfl_xor(v, 1, 64));
      v = fmaxf(v, __shfl_xor(v, 2, 64));
      v = fmaxf(v, __shfl_xor(v, 4, 64));
      v = fmaxf(v, __shfl_xor(v, 8, 64));
      if (s == 0) s_mrow[wave * 64 + rt * 16 + q * 4 + r] = v;
    }
  __syncthreads();

  float thr[4][4];
#pragma unroll
  for (int rt = 0; rt < 4; ++rt)
#pragma unroll
    for (int r = 0; r < 4; ++r)
      thr[rt][r] = s_mrow[wave * 64 + rt * 16 + q * 4 + r] - HALF_DELTA;

  // ---- sweep B: recompute S~ (bit-identical), emit candidates ----
#pragma unroll 4
  for (int t = 0; t < NT; ++t) {
    const frag8 b0 = pp[t * 128];
    const frag8 b1 = pp[t * 128 + 64];
    const int kl = t * 16 + s;
#pragma unroll
    for (int rt = 0; rt < 4; ++rt) {
      f32x4 d = {0.f, 0.f, 0.f, 0.f};
      d = __builtin_amdgcn_mfma_f32_16x16x32_bf16(afr[rt][0], b0, d, 0, 0, 0);
      d = __builtin_amdgcn_mfma_f32_16x16x32_bf16(afr[rt][1], b1, d, 0, 0, 0);
#pragma unroll
      for (int r = 0; r < 4; ++r) {
        if (d[r] >= thr[rt][r]) {
          const int pos = atomicAdd(&s_cnt, 1);
          if (pos < CAND_CAP)
            s_cand[pos] = ((unsigned)(wave * 64 + rt * 16 + q * 4 + r) << 10) | (unsigned)kl;
        }
      }
    }
  }
  __syncthreads();

  // ---- exact rescore of candidates (bit-exact numpy fp32 pipeline) ----
  const int cnt = min(s_cnt, CAND_CAP);
  for (int i = tid; i < cnt; i += 256) {
    const unsigned e = s_cand[i];
    const int row_l = (int)(e >> 10);
    const int kg = kbase + (int)(e & 0x3FFu);
    const float* ep = emb + (size_t)kg * DIM;
    const float* xp = xb + hw0 + row_l;
    float S = 0.f;
#pragma unroll
    for (int c = 0; c < DIM; ++c) S = __fmaf_rn(xp[(size_t)c * 1024], ep[c], S);
    const float dd = __fsub_rn(s_normx[row_l], __fadd_rn(S, S));
    const unsigned long long pack =
        ((unsigned long long)__float_as_uint(dd) << 13) | (unsigned long long)kg;
    atomicMin(&s_best[row_l], pack);
  }
  __syncthreads();

  wsbest[(size_t)(rowbase + tid) * 8 + blockIdx.y] = s_best[tid];
}

// ---- kernel 2: merge slices, write indices + gather z_q ----
__global__ __launch_bounds__(256) void vq_out(
    const float* __restrict__ emb, const unsigned long long* __restrict__ wsbest,
    float* __restrict__ zq, float* __restrict__ idx_out)
{
  const int row = blockIdx.x * 256 + threadIdx.x;
  unsigned long long p = wsbest[(size_t)row * 8];
#pragma unroll
  for (int j = 1; j < 8; ++j) {
    const unsigned long long pj = wsbest[(size_t)row * 8 + j];
    if (pj < p) p = pj;                        // d-major, then lowest k
  }
  const int k = (int)(p & 0x1FFFull);
  idx_out[row] = (float)k;
  const int b = row >> 10, hw = row & 1023;
  const float* ep = emb + (size_t)k * DIM;
  float* zp = zq + (size_t)b * (DIM * 1024) + hw;
#pragma unroll
  for (int c = 0; c < DIM; ++c) zp[(size_t)c * 1024] = ep[c];
}

extern "C" void kernel_launch(void* const* d_in, const int* in_sizes, int n_in,
                              void* d_out, int out_size, void* d_ws, size_t ws_size,
                              hipStream_t stream) {
  const float* x   = (const float*)d_in[0];   // [32, 64, 32, 32] fp32
  const float* emb = (const float*)d_in[1];   // [8192, 64] fp32

  float* zq      = (float*)d_out;
  float* idx_out = zq + (size_t)NROWS * DIM;

  unsigned short*     ebp    = (unsigned short*)d_ws;                          // 1 MB (permuted)
  unsigned long long* wsbest = (unsigned long long*)((char*)d_ws + (1 << 20)); // 2 MB

  cvt_emb<<<dim3(256), 256, 0, stream>>>(emb, ebp);
  vq_main<<<dim3(NROWS / RPB, NCODE / KQ), 256, 0, stream>>>(x, emb, ebp, wsbest);
  vq_out<<<dim3(NROWS / 256), 256, 0, stream>>>(emb, wsbest, zq, idx_out);
}